// Round 9
// baseline (359.806 us; speedup 1.0000x reference)
//
#include <hip/hip_runtime.h>
#include <hip/hip_bf16.h>
#include <hip/hip_cooperative_groups.h>

namespace cg = cooperative_groups;

#define NN 8192
#define FIN 128
#define FOUT 64
#define T 256
#define NWRD 128   // u64 words per mask row
#define NB 1024    // bytes per mask row

typedef __attribute__((ext_vector_type(8))) short short8;
typedef __attribute__((ext_vector_type(16))) float f32x16;
typedef unsigned int u32;
typedef unsigned char u8;
typedef unsigned long long u64;

union SMem {
    struct { float Xs[32][FIN + 1]; short Tt[32][72]; float yp[8][32]; } xw;
    struct { float ys[NN]; float red[4]; } mk;     // 32.8 KB (largest)
    struct { float red[4][2048]; } mm;             // 32 KB
    struct { float es[NN]; } dn;                   // 32 KB
    struct { short Tt[64][72]; } bb;               // 9 KB
};

static __device__ __forceinline__ short f2bf(float f) {
    union { __hip_bfloat16 h; short s; } u;
    u.h = __float2bfloat16(f);
    return u.s;
}
static __device__ __forceinline__ float decM(u32 u) {
    return __uint_as_float((u & 0x80000000u) ? (u & 0x7FFFFFFFu) : ~u);
}
// one mask byte -> 8 bf16 {0,1.0} packed in short8
static __device__ __forceinline__ short8 expand8(u32 b) {
    u32 xl = ((b & 0xFu) * 0x00204081u) & 0x01010101u;
    u32 xh = (((b >> 4) & 0xFu) * 0x00204081u) & 0x01010101u;
    u32 d0 = __builtin_amdgcn_perm(0u, xl, 0x0C010C00u) * 0x3F80u;
    u32 d1 = __builtin_amdgcn_perm(0u, xl, 0x0C030C02u) * 0x3F80u;
    u32 d2 = __builtin_amdgcn_perm(0u, xh, 0x0C010C00u) * 0x3F80u;
    u32 d3 = __builtin_amdgcn_perm(0u, xh, 0x0C030C02u) * 0x3F80u;
    union { u32 u[4]; short8 v; } r;
    r.u[0] = d0; r.u[1] = d1; r.u[2] = d2; r.u[3] = d3;
    return r.v;
}

// ---------------- phase 0 body: XW frag-major + y = XW@phi_j (vb < 256) ----------------
static __device__ __forceinline__ void ph_xw(SMem& sm, int vb, int t,
        const float* __restrict__ X, const float* __restrict__ W,
        const float* __restrict__ phi, short* __restrict__ XWf,
        float* __restrict__ y) {
    const int jb = vb * 32;
    for (int u = t; u < 32 * FIN; u += T) {
        int r = u >> 7, k = u & (FIN - 1);
        sm.xw.Xs[r][k] = X[(size_t)(jb + r) * FIN + k];
    }
    __syncthreads();
    const int j = t & 31;
    const int cg8 = t >> 5;
    float acc[8] = {};
    for (int k = 0; k < FIN; ++k) {
        float x = sm.xw.Xs[j][k];
        #pragma unroll
        for (int q = 0; q < 8; ++q)
            acc[q] = fmaf(x, W[k * FOUT + cg8 * 8 + q], acc[q]);
    }
    float ys = 0.f;
    union { short s[8]; short8 v; } pk;
    #pragma unroll
    for (int q = 0; q < 8; ++q) {
        ys = fmaf(acc[q], phi[FOUT + cg8 * 8 + q], ys);
        pk.s[q] = f2bf(acc[q]);
    }
    *(short8*)&sm.xw.Tt[j][cg8 * 8] = pk.v;
    sm.xw.yp[cg8][j] = ys;
    __syncthreads();
    if (t < 32) {
        float s = 0.f;
        #pragma unroll
        for (int g2 = 0; g2 < 8; ++g2) s += sm.xw.yp[g2][t];
        y[jb + t] = s;
    }
    {
        int f = t >> 6, ln = t & 63;
        int c = (f & 1) * 32 + (ln & 31);
        int j0 = (f >> 1) * 16 + (ln >> 5) * 8;
        union { short s[8]; short8 v; } w8;
        #pragma unroll
        for (int e = 0; e < 8; ++e) w8.s[e] = sm.xw.Tt[j0 + e][c];
        size_t fg = ((size_t)(jb >> 4) + (f >> 1)) * 2 + (f & 1);
        *(short8*)&XWf[fg * 512 + ln * 8] = w8.v;
    }
    __syncthreads();
}

// ---------------- phase 1 body: 8 rows of A -> bits + exact sj (vb < 1024) -------------
// requires sm.mk.ys staged; returns lane0-valid local max
static __device__ __forceinline__ float ph_mask_vb(SMem& sm, int vb, int t,
        const float* __restrict__ A, const float* __restrict__ cb,
        u8* __restrict__ m8, float* __restrict__ sjv) {
    const int l = t & 63, w = t >> 6;
    const float* ysp = sm.mk.ys;
    float mloc = -3.0e38f;
    #pragma unroll
    for (int h = 0; h < 2; ++h) {
        const int row = vb * 8 + w + h * 4;
        const float* ar = A + (size_t)row * NN + l * 8;
        u8* mr = m8 + (size_t)row * NB + l;
        float s = 0.f;
        #pragma unroll 2
        for (int kc = 0; kc < NN; kc += 512) {
            float4 a = *(const float4*)(ar + kc);
            float4 b4 = *(const float4*)(ar + kc + 4);
            float4 y0 = *(const float4*)(ysp + kc + l * 8);
            float4 y1 = *(const float4*)(ysp + kc + l * 8 + 4);
            s = fmaf(a.x, y0.x, s); s = fmaf(a.y, y0.y, s);
            s = fmaf(a.z, y0.z, s); s = fmaf(a.w, y0.w, s);
            s = fmaf(b4.x, y1.x, s); s = fmaf(b4.y, y1.y, s);
            s = fmaf(b4.z, y1.z, s); s = fmaf(b4.w, y1.w, s);
            u32 x0 = __float_as_uint(a.x), x1 = __float_as_uint(a.y);
            u32 x2 = __float_as_uint(a.z), x3 = __float_as_uint(a.w);
            u32 x4 = __float_as_uint(b4.x), x5 = __float_as_uint(b4.y);
            u32 x6 = __float_as_uint(b4.z), x7 = __float_as_uint(b4.w);
            u32 ylo = __builtin_amdgcn_perm(x1, x0, 0x0C0C0703u) |
                      __builtin_amdgcn_perm(x3, x2, 0x07030C0Cu);
            u32 yhi = __builtin_amdgcn_perm(x5, x4, 0x0C0C0703u) |
                      __builtin_amdgcn_perm(x7, x6, 0x07030C0Cu);
            u32 nlo = (((ylo >> 5) & 0x01010101u) * 0x01020408u) >> 24;
            u32 nhi = (((yhi >> 5) & 0x01010101u) * 0x01020408u) >> 24;
            mr[kc >> 3] = (u8)(nlo | (nhi << 4));
        }
        #pragma unroll
        for (int o = 32; o >= 1; o >>= 1) s += __shfl_down(s, o, 64);
        if (l == 0) {
            float sj = s + cb[0];
            sjv[row] = sj;
            mloc = fmaxf(mloc, sj);
        }
    }
    return mloc;
}

// ---------------- mm body: mask(A[+I]) @ Bfrag, vb < 1024 (mt=vb>>2, ks=vb&3) ----------
static __device__ __forceinline__ void mm_phase(SMem& sm, const u64* mask,
        const short* __restrict__ Bfrag, float* __restrict__ outp,
        int vb, int t, bool diag) {
    const int mt = vb >> 2, ks = vb & 3;
    const int l = t & 63, w = t >> 6;
    const int r0 = mt * 32 + (l & 31);
    const int kh = l >> 5;
    const int k0 = ks * 2048 + w * 512;

    const u64* mp = mask + (size_t)r0 * NWRD + (k0 >> 6);
    u64 mw[8];
    #pragma unroll
    for (int q = 0; q < 8; ++q) mw[q] = mp[q];

    f32x16 acc0 = {}, acc1 = {};
    const short* bp = Bfrag + (size_t)(k0 >> 4) * 1024 + l * 8;
    short8 e0f0 = *(const short8*)(bp);
    short8 e0f1 = *(const short8*)(bp + 512);
    short8 e1f0 = *(const short8*)(bp + 1024);
    short8 e1f1 = *(const short8*)(bp + 1536);

    #pragma unroll
    for (int kt = 0; kt < 32; ++kt) {
        u32 bby = (u32)(mw[kt >> 2] >> (((kt & 3) * 2 + kh) * 8)) & 0xFFu;
        if (diag) {
            u32 d = (u32)(r0 - (k0 + kt * 16 + kh * 8));
            if (d < 8u) bby |= 1u << d;
        }
        short8 af = expand8(bby);
        short8 bf0 = (kt & 1) ? e1f0 : e0f0;
        short8 bf1 = (kt & 1) ? e1f1 : e0f1;
        if (kt + 2 < 32) {
            short8 n0 = *(const short8*)(bp + (kt + 2) * 1024);
            short8 n1 = *(const short8*)(bp + (kt + 2) * 1024 + 512);
            if (kt & 1) { e1f0 = n0; e1f1 = n1; } else { e0f0 = n0; e0f1 = n1; }
        }
        acc0 = __builtin_amdgcn_mfma_f32_32x32x16_bf16(af, bf0, acc0, 0, 0, 0);
        acc1 = __builtin_amdgcn_mfma_f32_32x32x16_bf16(af, bf1, acc1, 0, 0, 0);
    }

    const int cc = l & 31;
    float* rw = sm.mm.red[w];
    #pragma unroll
    for (int q = 0; q < 16; ++q) {
        int row = (q & 3) + 8 * (q >> 2) + 4 * kh;
        rw[row * 64 + cc] = acc0[q];
        rw[row * 64 + 32 + cc] = acc1[q];
    }
    __syncthreads();
    float* dst = outp + ((size_t)ks * NN + mt * 32) * 64;
    #pragma unroll
    for (int part = 0; part < 2; ++part) {
        int x = t * 8 + part * 4;
        float4 s = {0.f, 0.f, 0.f, 0.f};
        #pragma unroll
        for (int ww = 0; ww < 4; ++ww) {
            float4 v = *(const float4*)&sm.mm.red[ww][x];
            s.x += v.x; s.y += v.y; s.z += v.z; s.w += v.w;
        }
        *(float4*)&dst[x] = s;
    }
    __syncthreads();
}

// ---------------- phase 3a body: B2 build (vb < 128) ----------------
static __device__ __forceinline__ void ph_bbuild(SMem& sm, int vb, int t,
        const float* __restrict__ aggp, const float* __restrict__ bias,
        const float* __restrict__ sjv, const u32* __restrict__ MbU,
        short* __restrict__ B2f) {
    const float M = decM(MbU[0]);
    const int jb = vb * 64;
    const int jl = t >> 2;
    const int j = jb + jl;
    const int cg4 = (t & 3) * 16;
    float v[16] = {};
    #pragma unroll
    for (int ks = 0; ks < 4; ++ks) {
        const float4* p = (const float4*)&aggp[((size_t)ks * NN + j) * 64 + cg4];
        float4 q0 = p[0], q1 = p[1], q2 = p[2], q3 = p[3];
        v[0] += q0.x; v[1] += q0.y; v[2] += q0.z; v[3] += q0.w;
        v[4] += q1.x; v[5] += q1.y; v[6] += q1.z; v[7] += q1.w;
        v[8] += q2.x; v[9] += q2.y; v[10] += q2.z; v[11] += q2.w;
        v[12] += q3.x; v[13] += q3.y; v[14] += q3.z; v[15] += q3.w;
    }
    const float e = __expf(sjv[j] - M);
    union { short s[16]; short8 w[2]; } pk;
    #pragma unroll
    for (int q = 0; q < 16; ++q) pk.s[q] = f2bf((v[q] + bias[cg4 + q]) * e);
    *(short8*)&sm.bb.Tt[jl][cg4] = pk.w[0];
    *(short8*)&sm.bb.Tt[jl][cg4 + 8] = pk.w[1];
    __syncthreads();
    #pragma unroll
    for (int uu = 0; uu < 2; ++uu) {
        int u = t + uu * 256;
        int f = u >> 6, ln = u & 63;
        int c = (f & 1) * 32 + (ln & 31);
        int j0 = (f >> 1) * 16 + (ln >> 5) * 8;
        union { short s[8]; short8 v; } w8;
        #pragma unroll
        for (int e8 = 0; e8 < 8; ++e8) w8.s[e8] = sm.bb.Tt[j0 + e8][c];
        size_t fg = ((size_t)(jb >> 4) + (f >> 1)) * 2 + (f & 1);
        *(short8*)&B2f[fg * 512 + ln * 8] = w8.v;
    }
    __syncthreads();
}

// ---------------- phase 3b body: den rows (vb < 512), needs sm.dn.es staged ------------
static __device__ __forceinline__ void ph_den(SMem& sm, int vb, int t,
        const u64* __restrict__ mask, float* __restrict__ den) {
    const float* es = sm.dn.es;
    const int row = vb * 16 + (t >> 4);
    const int cs = t & 15;
    const u64* mp = mask + (size_t)row * NWRD + cs * 8;
    float s = 0.f;
    #pragma unroll
    for (int wd = 0; wd < 8; ++wd) {
        u64 mwv = mp[wd];
        const int kg = cs * 512 + wd * 64;
        u32 d = (u32)(row - kg);
        if (d < 64u) mwv |= 1ull << d;     // +I
        #pragma unroll
        for (int b8 = 0; b8 < 8; ++b8) {
            u32 by = (u32)(mwv >> (b8 * 8)) & 0xFFu;
            u32 xl = ((by & 0xFu) * 0x00204081u) & 0x01010101u;
            u32 xh = (((by >> 4) & 0xFu) * 0x00204081u) & 0x01010101u;
            u32 d0 = __builtin_amdgcn_perm(0u, xl, 0x0C010C00u) * 0x3F80u;
            u32 d1 = __builtin_amdgcn_perm(0u, xl, 0x0C030C02u) * 0x3F80u;
            u32 d2 = __builtin_amdgcn_perm(0u, xh, 0x0C010C00u) * 0x3F80u;
            u32 d3 = __builtin_amdgcn_perm(0u, xh, 0x0C030C02u) * 0x3F80u;
            const float* ep = es + kg + b8 * 8;
            s = fmaf(__uint_as_float(d0 << 16), ep[0], s);
            s = fmaf(__uint_as_float(d0 & 0xFFFF0000u), ep[1], s);
            s = fmaf(__uint_as_float(d1 << 16), ep[2], s);
            s = fmaf(__uint_as_float(d1 & 0xFFFF0000u), ep[3], s);
            s = fmaf(__uint_as_float(d2 << 16), ep[4], s);
            s = fmaf(__uint_as_float(d2 & 0xFFFF0000u), ep[5], s);
            s = fmaf(__uint_as_float(d3 << 16), ep[6], s);
            s = fmaf(__uint_as_float(d3 & 0xFFFF0000u), ep[7], s);
        }
    }
    #pragma unroll
    for (int o = 8; o >= 1; o >>= 1) s += __shfl_xor(s, o, 64);
    if (cs == 0) den[row] = s;
}

// ---------------- phase 5 body: out = relu(sum(hp)/den) (vb < 1024) --------------------
static __device__ __forceinline__ void ph_final(int vb, int t,
        const float* __restrict__ hp, const float* __restrict__ den,
        float* __restrict__ out) {
    const int idx0 = vb * 512;
    #pragma unroll
    for (int part = 0; part < 2; ++part) {
        int idx = idx0 + part * 256 + t;
        float num = 0.f;
        #pragma unroll
        for (int ks = 0; ks < 4; ++ks)
            num += hp[(size_t)ks * NN * 64 + idx];
        float v = num / den[idx >> 6];
        out[idx] = v > 0.f ? v : 0.f;
    }
}

// ================= cooperative mega-kernel (grid-stride, any grid size) ================
__global__ __launch_bounds__(T, 2) void gat_coop(
        const float* __restrict__ A, const float* __restrict__ X,
        const float* __restrict__ W, const float* __restrict__ bias,
        const float* __restrict__ phi, float* __restrict__ out,
        u8* __restrict__ m8, short* __restrict__ XWf, float* __restrict__ y,
        float* __restrict__ cb, u32* __restrict__ MbU, float* __restrict__ sjv,
        float* __restrict__ aggp, short* __restrict__ B2f,
        float* __restrict__ den, float* __restrict__ hp) {
    __shared__ SMem sm;
    cg::grid_group grid = cg::this_grid();
    const int b = blockIdx.x;
    const int t = threadIdx.x;
    const int G = gridDim.x;

    for (int vb = b; vb < 256; vb += G) ph_xw(sm, vb, t, X, W, phi, XWf, y);
    if (b == 0 && t == 0) {
        float s = 0.f;
        for (int c2 = 0; c2 < FOUT; ++c2) s = fmaf(bias[c2], phi[FOUT + c2], s);
        cb[0] = s;
        MbU[0] = 0u;
    }
    grid.sync();

    {   // phase 1
        for (int u = t; u < NN / 4; u += T)
            ((float4*)sm.mk.ys)[u] = ((const float4*)y)[u];
        __syncthreads();
        float mloc = -3.0e38f;
        for (int vb = b; vb < 1024; vb += G)
            mloc = fmaxf(mloc, ph_mask_vb(sm, vb, t, A, cb, m8, sjv));
        const int l = t & 63, w = t >> 6;
        if (l == 0) sm.mk.red[w] = mloc;
        __syncthreads();
        if (t == 0) {
            float bm = fmaxf(fmaxf(sm.mk.red[0], sm.mk.red[1]),
                             fmaxf(sm.mk.red[2], sm.mk.red[3]));
            u32 bits = __float_as_uint(bm);
            u32 enc = (bits & 0x80000000u) ? ~bits : (bits | 0x80000000u);
            atomicMax(MbU, enc);
        }
        __syncthreads();
    }
    grid.sync();

    for (int vb = b; vb < 1024; vb += G)
        mm_phase(sm, (const u64*)m8, XWf, aggp, vb, t, false);
    grid.sync();

    {   // phase 3: bbuild then den
        for (int vb = b; vb < 128; vb += G)
            ph_bbuild(sm, vb, t, aggp, bias, sjv, MbU, B2f);
        __syncthreads();
        const float M = decM(MbU[0]);
        for (int i = t; i < NN; i += T) sm.dn.es[i] = __expf(sjv[i] - M);
        __syncthreads();
        for (int vb = b; vb < 512; vb += G)
            ph_den(sm, vb, t, (const u64*)m8, den);
    }
    grid.sync();

    for (int vb = b; vb < 1024; vb += G)
        mm_phase(sm, (const u64*)m8, B2f, hp, vb, t, true);
    grid.sync();

    for (int vb = b; vb < 1024; vb += G) ph_final(vb, t, hp, den, out);
}

// ================= fallback wrappers (multi-kernel path) ================
__global__ __launch_bounds__(T) void k_xw(const float* X, const float* W,
        const float* bias, const float* phi, short* XWf, float* y,
        float* cb, u32* MbU) {
    __shared__ SMem sm;
    ph_xw(sm, blockIdx.x, threadIdx.x, X, W, phi, XWf, y);
    if (blockIdx.x == 0 && threadIdx.x == 0) {
        float s = 0.f;
        for (int c2 = 0; c2 < FOUT; ++c2) s = fmaf(bias[c2], phi[FOUT + c2], s);
        cb[0] = s;
        MbU[0] = 0u;
    }
}
__global__ __launch_bounds__(T) void k_mask(const float* A, const float* y,
        const float* cb, u8* m8, float* sjv, u32* MbU) {
    __shared__ SMem sm;
    const int t = threadIdx.x;
    for (int u = t; u < NN / 4; u += T)
        ((float4*)sm.mk.ys)[u] = ((const float4*)y)[u];
    __syncthreads();
    float mloc = ph_mask_vb(sm, blockIdx.x, t, A, cb, m8, sjv);
    const int l = t & 63, w = t >> 6;
    if (l == 0) sm.mk.red[w] = mloc;
    __syncthreads();
    if (t == 0) {
        float bm = fmaxf(fmaxf(sm.mk.red[0], sm.mk.red[1]),
                         fmaxf(sm.mk.red[2], sm.mk.red[3]));
        u32 bits = __float_as_uint(bm);
        u32 enc = (bits & 0x80000000u) ? ~bits : (bits | 0x80000000u);
        atomicMax(MbU, enc);
    }
}
template <bool DIAG>
__global__ __launch_bounds__(T) void k_mm(const u64* mask, const short* Bfrag,
                                          float* outp) {
    __shared__ SMem sm;
    mm_phase(sm, mask, Bfrag, outp, blockIdx.x, threadIdx.x, DIAG);
}
__global__ __launch_bounds__(T) void k_ph3(const float* aggp, const float* bias,
        const float* sjv, const u32* MbU, short* B2f, const u64* mask,
        float* den) {
    __shared__ SMem sm;
    const int b = blockIdx.x, t = threadIdx.x;
    if (b < 128) {
        ph_bbuild(sm, b, t, aggp, bias, sjv, MbU, B2f);
    } else {
        const float M = decM(MbU[0]);
        for (int i = t; i < NN; i += T) sm.dn.es[i] = __expf(sjv[i] - M);
        __syncthreads();
        ph_den(sm, b - 128, t, mask, den);
    }
}
__global__ __launch_bounds__(T) void k_final(const float* hp, const float* den,
                                             float* out) {
    ph_final(blockIdx.x, threadIdx.x, hp, den, out);
}

extern "C" void kernel_launch(void* const* d_in, const int* in_sizes, int n_in,
                              void* d_out, int out_size, void* d_ws, size_t ws_size,
                              hipStream_t stream) {
    const float* A    = (const float*)d_in[0];
    const float* X    = (const float*)d_in[1];
    const float* W    = (const float*)d_in[2];
    const float* bias = (const float*)d_in[3];
    const float* phi  = (const float*)d_in[4];
    float* out = (float*)d_out;

    char* ws = (char*)d_ws;
    size_t off = 0;
    auto alloc = [&](size_t bytes) -> void* {
        void* p = ws + off;
        off += (bytes + 255) & ~(size_t)255;
        return p;
    };
    u8*    m8   = (u8*)alloc((size_t)NN * NB);
    short* XWf  = (short*)alloc((size_t)FOUT * NN * 2);
    float* y    = (float*)alloc((size_t)NN * 4);
    float* cb   = (float*)alloc(256);
    u32*   MbU  = (u32*)alloc(256);
    float* sjv  = (float*)alloc((size_t)NN * 4);
    float* aggp = (float*)alloc((size_t)4 * NN * FOUT * 4);
    short* B2f  = (short*)alloc((size_t)FOUT * NN * 2);
    float* den  = (float*)alloc((size_t)NN * 4);
    float* hp   = (float*)alloc((size_t)4 * NN * FOUT * 4);

    int dev = 0;
    (void)hipGetDevice(&dev);
    int coopOK = 0, ncu = 0, maxb = 0;
    (void)hipDeviceGetAttribute(&coopOK, hipDeviceAttributeCooperativeLaunch, dev);
    (void)hipDeviceGetAttribute(&ncu, hipDeviceAttributeMultiprocessorCount, dev);
    (void)hipOccupancyMaxActiveBlocksPerMultiprocessor(&maxb, (const void*)gat_coop, T, 0);

    long Gl = (long)maxb * (long)ncu;
    if (Gl > 1024) Gl = 1024;

    bool done = false;
    if (coopOK && Gl >= 64) {
        void* args[] = { (void*)&A, (void*)&X, (void*)&W, (void*)&bias, (void*)&phi,
                         (void*)&out, (void*)&m8, (void*)&XWf, (void*)&y, (void*)&cb,
                         (void*)&MbU, (void*)&sjv, (void*)&aggp, (void*)&B2f,
                         (void*)&den, (void*)&hp };
        hipError_t e = hipLaunchCooperativeKernel((void*)gat_coop,
                dim3((unsigned)Gl), dim3(T), args, 0, stream);
        done = (e == hipSuccess);
    }
    if (!done) {
        k_xw<<<256, T, 0, stream>>>(X, W, bias, phi, XWf, y, cb, MbU);
        k_mask<<<1024, T, 0, stream>>>(A, y, cb, m8, sjv, MbU);
        k_mm<false><<<1024, T, 0, stream>>>((const u64*)m8, XWf, aggp);
        k_ph3<<<640, T, 0, stream>>>(aggp, bias, sjv, MbU, B2f, (const u64*)m8, den);
        k_mm<true><<<1024, T, 0, stream>>>((const u64*)m8, B2f, hp);
        k_final<<<1024, T, 0, stream>>>(hp, den, out);
    }
}

// Round 10
// 176.759 us; speedup vs baseline: 2.0356x; 2.0356x over previous
//
#include <hip/hip_runtime.h>
#include <hip/hip_bf16.h>

#define NN 8192
#define FIN 128
#define FOUT 64
#define NWRD (NN / 64)       // 128 u64 words per mask row
#define NB (NN / 8)          // 1024 mask bytes per row

typedef __attribute__((ext_vector_type(8))) short short8;
typedef __attribute__((ext_vector_type(16))) float f32x16;
typedef unsigned int u32;
typedef unsigned char u8;
typedef unsigned long long u64;

static __device__ __forceinline__ short f2bf(float f) {
    union { __hip_bfloat16 h; short s; } u;
    u.h = __float2bfloat16(f);
    return u.s;
}
static __device__ __forceinline__ float decM(u32 u) {
    return __uint_as_float((u & 0x80000000u) ? (u & 0x7FFFFFFFu) : ~u);
}

// one mask byte (8 bits) -> 8 bf16 {0,1.0} packed in short8
static __device__ __forceinline__ short8 expand8(u32 b) {
    u32 xl = ((b & 0xFu) * 0x00204081u) & 0x01010101u;
    u32 xh = (((b >> 4) & 0xFu) * 0x00204081u) & 0x01010101u;
    u32 d0 = __builtin_amdgcn_perm(0u, xl, 0x0C010C00u) * 0x3F80u;
    u32 d1 = __builtin_amdgcn_perm(0u, xl, 0x0C030C02u) * 0x3F80u;
    u32 d2 = __builtin_amdgcn_perm(0u, xh, 0x0C010C00u) * 0x3F80u;
    u32 d3 = __builtin_amdgcn_perm(0u, xh, 0x0C030C02u) * 0x3F80u;
    union { u32 u[4]; short8 v; } r;
    r.u[0] = d0; r.u[1] = d1; r.u[2] = d2; r.u[3] = d3;
    return r.v;
}

// ---------- XW (no bias) -> fragment-major bf16 + y = XW@phi_j; init cb/Mb ----------
__global__ __launch_bounds__(256) void xw_kernel(const float* __restrict__ X,
        const float* __restrict__ W, const float* __restrict__ bias,
        const float* __restrict__ phi, short* __restrict__ XWf,
        float* __restrict__ y, float* __restrict__ cb, u32* __restrict__ MbU) {
    __shared__ float Xs[64][FIN + 1];
    __shared__ short T[64][72];     // [node j][col c] bf16, padded
    __shared__ float yp[4][64];
    const int t = threadIdx.x;
    const int jb = blockIdx.x * 64;
    for (int u = t; u < 64 * FIN; u += 256) {
        int r = u >> 7, k = u & (FIN - 1);
        Xs[r][k] = X[(size_t)(jb + r) * FIN + k];
    }
    __syncthreads();
    const int j = t & 63;
    const int cg = t >> 6;
    float acc[16] = {};
    for (int k = 0; k < FIN; ++k) {
        float x = Xs[j][k];
        #pragma unroll
        for (int q = 0; q < 16; ++q)
            acc[q] = fmaf(x, W[k * FOUT + cg * 16 + q], acc[q]);
    }
    float ys = 0.f;
    union { short s[16]; short8 v[2]; } pk;
    #pragma unroll
    for (int q = 0; q < 16; ++q) {
        ys = fmaf(acc[q], phi[FOUT + cg * 16 + q], ys);
        pk.s[q] = f2bf(acc[q]);
    }
    *(short8*)&T[j][cg * 16] = pk.v[0];
    *(short8*)&T[j][cg * 16 + 8] = pk.v[1];
    yp[cg][j] = ys;
    __syncthreads();
    if (t < 64) y[jb + t] = yp[0][t] + yp[1][t] + yp[2][t] + yp[3][t];
    if (blockIdx.x == 0 && t == 0) {
        float s = 0.f;
        for (int c = 0; c < FOUT; ++c) s = fmaf(bias[c], phi[FOUT + c], s);
        cb[0] = s;
        MbU[0] = 0u;   // encoded -inf sentinel for atomicMax
    }
    // fragment-major: frag fi = ktile*2 + colgroup; lane l: B[k=(l>>5)*8+e][c=(l&31)]
    #pragma unroll
    for (int uu = 0; uu < 2; ++uu) {
        int u = t + uu * 256;
        int f = u >> 6, ln = u & 63;
        int c = (f & 1) * 32 + (ln & 31);
        int j0 = (f >> 1) * 16 + (ln >> 5) * 8;
        union { short s[8]; short8 v; } w8;
        #pragma unroll
        for (int e = 0; e < 8; ++e) w8.s[e] = T[j0 + e][c];
        size_t fg = ((size_t)(jb >> 4) + (f >> 1)) * 2 + (f & 1);
        *(short8*)&XWf[fg * 512 + ln * 8] = w8.v;
    }
}

// ---------- A -> bitmask bytes; fused exact sj = A@y + cb; atomicMax global max -------
// NO LDS staging (y read from global, L1/L2-resident) -> no bank conflicts, high occ.
__global__ __launch_bounds__(256) void mask_kernel(const float* __restrict__ A,
        const float* __restrict__ y, const float* __restrict__ cb,
        u8* __restrict__ m8, float* __restrict__ sjv, u32* __restrict__ MbU) {
    __shared__ float red[4];
    const int t = threadIdx.x;
    const int w = t >> 6, l = t & 63;
    const int row = blockIdx.x * 4 + w;
    const float* ar = A + (size_t)row * NN + l * 8;
    const float* yr = y + l * 8;
    u8* mr = m8 + (size_t)row * NB + l;
    float s = 0.f;
    #pragma unroll 4
    for (int kc = 0; kc < NN; kc += 512) {
        float4 a = *(const float4*)(ar + kc);
        float4 b4 = *(const float4*)(ar + kc + 4);
        float4 y0 = *(const float4*)(yr + kc);
        float4 y1 = *(const float4*)(yr + kc + 4);
        s = fmaf(a.x, y0.x, s); s = fmaf(a.y, y0.y, s);
        s = fmaf(a.z, y0.z, s); s = fmaf(a.w, y0.w, s);
        s = fmaf(b4.x, y1.x, s); s = fmaf(b4.y, y1.y, s);
        s = fmaf(b4.z, y1.z, s); s = fmaf(b4.w, y1.w, s);
        u32 x0 = __float_as_uint(a.x), x1 = __float_as_uint(a.y);
        u32 x2 = __float_as_uint(a.z), x3 = __float_as_uint(a.w);
        u32 x4 = __float_as_uint(b4.x), x5 = __float_as_uint(b4.y);
        u32 x6 = __float_as_uint(b4.z), x7 = __float_as_uint(b4.w);
        u32 ylo = __builtin_amdgcn_perm(x1, x0, 0x0C0C0703u) |
                  __builtin_amdgcn_perm(x3, x2, 0x07030C0Cu);
        u32 yhi = __builtin_amdgcn_perm(x5, x4, 0x0C0C0703u) |
                  __builtin_amdgcn_perm(x7, x6, 0x07030C0Cu);
        u32 nlo = (((ylo >> 5) & 0x01010101u) * 0x01020408u) >> 24;
        u32 nhi = (((yhi >> 5) & 0x01010101u) * 0x01020408u) >> 24;
        mr[kc >> 3] = (u8)(nlo | (nhi << 4));
    }
    #pragma unroll
    for (int o = 32; o >= 1; o >>= 1) s += __shfl_down(s, o, 64);
    if (l == 0) {
        float sj = s + cb[0];
        sjv[row] = sj;
        red[w] = sj;
    }
    __syncthreads();
    if (t == 0) {
        float bm = fmaxf(fmaxf(red[0], red[1]), fmaxf(red[2], red[3]));
        u32 bits = __float_as_uint(bm);
        u32 enc = (bits & 0x80000000u) ? ~bits : (bits | 0x80000000u);
        atomicMax(MbU, enc);
    }
}

// ---------- mask(A[+I]) @ B : full-K per block, no split-K partials (R5-proven) -------
// 256 blocks x 32 rows; 8 waves each own K=1024; B-frags global->VGPR (L2-hit).
template <bool DIAG>
__global__ __launch_bounds__(512) void mm_kernel(const u64* __restrict__ mask,
        const short* __restrict__ Bfrag, float* __restrict__ outv) {
    __shared__ float red[8][2048];
    const int t = threadIdx.x;
    const int w = t >> 6;          // wave 0..7
    const int l = t & 63;
    const int brow = blockIdx.x * 32;
    const int r0 = brow + (l & 31);
    const int kh = l >> 5;
    const int k0 = w * 1024;       // wave's K-chunk base

    const u64* mp = mask + (size_t)r0 * NWRD + (k0 >> 6);
    u64 mw[16];
    #pragma unroll
    for (int q = 0; q < 16; ++q) mw[q] = mp[q];

    f32x16 acc0 = {}, acc1 = {};
    const short* bp = Bfrag + (size_t)(k0 >> 4) * 2 * 512 + l * 8;

    short8 f0a, f1a, f0b, f1b, f0c, f1c, f0d, f1d;
    f0a = *(const short8*)(bp + 0 * 512);  f1a = *(const short8*)(bp + 1 * 512);
    f0b = *(const short8*)(bp + 2 * 512);  f1b = *(const short8*)(bp + 3 * 512);
    f0c = *(const short8*)(bp + 4 * 512);  f1c = *(const short8*)(bp + 5 * 512);
    f0d = *(const short8*)(bp + 6 * 512);  f1d = *(const short8*)(bp + 7 * 512);

    #pragma unroll
    for (int kt4 = 0; kt4 < 16; ++kt4) {
        #pragma unroll
        for (int pp = 0; pp < 4; ++pp) {
            const int kt = kt4 * 4 + pp;
            const int bidx = kt * 2 + kh;
            u32 b = (u32)(mw[bidx >> 3] >> ((bidx & 7) * 8)) & 0xFFu;
            if (DIAG) {
                u32 d = (u32)(r0 - (k0 + kt * 16 + kh * 8));
                if (d < 8u) b |= 1u << d;
            }
            short8 a = expand8(b);
            short8 bf0 = (pp == 0) ? f0a : (pp == 1) ? f0b : (pp == 2) ? f0c : f0d;
            short8 bf1 = (pp == 0) ? f1a : (pp == 1) ? f1b : (pp == 2) ? f1c : f1d;
            acc0 = __builtin_amdgcn_mfma_f32_32x32x16_bf16(a, bf0, acc0, 0, 0, 0);
            acc1 = __builtin_amdgcn_mfma_f32_32x32x16_bf16(a, bf1, acc1, 0, 0, 0);
            if (kt + 4 < 64) {
                short8 n0 = *(const short8*)(bp + ((kt + 4) * 2 + 0) * 512);
                short8 n1 = *(const short8*)(bp + ((kt + 4) * 2 + 1) * 512);
                if (pp == 0) { f0a = n0; f1a = n1; }
                else if (pp == 1) { f0b = n0; f1b = n1; }
                else if (pp == 2) { f0c = n0; f1c = n1; }
                else { f0d = n0; f1d = n1; }
            }
        }
    }

    // cross-wave reduce in LDS: D layout col=lane&31, row=(q&3)+8*(q>>2)+4*(lane>>5)
    const int cc = l & 31;
    const int rq4 = 4 * (l >> 5);
    #pragma unroll
    for (int q = 0; q < 16; ++q) {
        int row = (q & 3) + 8 * (q >> 2) + rq4;
        red[w][row * 64 + cc] = acc0[q];
        red[w][row * 64 + 32 + cc] = acc1[q];
    }
    __syncthreads();
    float4 s = {0.f, 0.f, 0.f, 0.f};
    #pragma unroll
    for (int ww = 0; ww < 8; ++ww) {
        float4 v = *(const float4*)&red[ww][t * 4];
        s.x += v.x; s.y += v.y; s.z += v.z; s.w += v.w;
    }
    *(float4*)&outv[(size_t)brow * 64 + t * 4] = s;
}

// ---------- fused: bbuild (blocks 0..127) | den (blocks 128..639) ----------
__global__ __launch_bounds__(256) void ph3_kernel(const float* __restrict__ aggr,
        const float* __restrict__ bias, const float* __restrict__ sjv,
        const u32* __restrict__ MbU, short* __restrict__ B2f,
        const u64* __restrict__ mask, float* __restrict__ den) {
    __shared__ union { short Tt[64][72]; float es[NN]; } sm;
    const int b = blockIdx.x, t = threadIdx.x;
    if (b < 128) {
        // B2 = bf16(e_j * (agg_j + bias)) in fragment-major
        const int jb = b * 64;
        const int jl = t >> 2;
        const int j = jb + jl;
        const int cg = (t & 3) * 16;
        const float4* p = (const float4*)&aggr[(size_t)j * 64 + cg];
        float4 q0 = p[0], q1 = p[1], q2 = p[2], q3 = p[3];
        float v[16] = {q0.x, q0.y, q0.z, q0.w, q1.x, q1.y, q1.z, q1.w,
                       q2.x, q2.y, q2.z, q2.w, q3.x, q3.y, q3.z, q3.w};
        const float e = __expf(sjv[j] - decM(MbU[0]));
        union { short s[16]; short8 w[2]; } pk;
        #pragma unroll
        for (int q = 0; q < 16; ++q) pk.s[q] = f2bf((v[q] + bias[cg + q]) * e);
        *(short8*)&sm.Tt[jl][cg] = pk.w[0];
        *(short8*)&sm.Tt[jl][cg + 8] = pk.w[1];
        __syncthreads();
        #pragma unroll
        for (int uu = 0; uu < 2; ++uu) {
            int u = t + uu * 256;
            int f = u >> 6, ln = u & 63;
            int c = (f & 1) * 32 + (ln & 31);
            int j0 = (f >> 1) * 16 + (ln >> 5) * 8;
            union { short s[8]; short8 v; } w8;
            #pragma unroll
            for (int e8 = 0; e8 < 8; ++e8) w8.s[e8] = sm.Tt[j0 + e8][c];
            size_t fg = ((size_t)(jb >> 4) + (f >> 1)) * 2 + (f & 1);
            *(short8*)&B2f[fg * 512 + ln * 8] = w8.v;
        }
    } else {
        // den_i = sum_{j in mask+I} e_j
        const float M = decM(MbU[0]);
        for (int i = t; i < NN; i += 256) sm.es[i] = __expf(sjv[i] - M);
        __syncthreads();
        const float* es = sm.es;
        const int row = (b - 128) * 16 + (t >> 4);
        const int cs = t & 15;
        const u64* mp = mask + (size_t)row * NWRD + cs * 8;
        float s = 0.f;
        #pragma unroll
        for (int wd = 0; wd < 8; ++wd) {
            u64 mwv = mp[wd];
            const int kg = cs * 512 + wd * 64;
            u32 d = (u32)(row - kg);
            if (d < 64u) mwv |= 1ull << d;     // +I
            #pragma unroll
            for (int b8 = 0; b8 < 8; ++b8) {
                u32 by = (u32)(mwv >> (b8 * 8)) & 0xFFu;
                u32 xl = ((by & 0xFu) * 0x00204081u) & 0x01010101u;
                u32 xh = (((by >> 4) & 0xFu) * 0x00204081u) & 0x01010101u;
                u32 d0 = __builtin_amdgcn_perm(0u, xl, 0x0C010C00u) * 0x3F80u;
                u32 d1 = __builtin_amdgcn_perm(0u, xl, 0x0C030C02u) * 0x3F80u;
                u32 d2 = __builtin_amdgcn_perm(0u, xh, 0x0C010C00u) * 0x3F80u;
                u32 d3 = __builtin_amdgcn_perm(0u, xh, 0x0C030C02u) * 0x3F80u;
                const float* ep = es + kg + b8 * 8;
                s = fmaf(__uint_as_float(d0 << 16), ep[0], s);
                s = fmaf(__uint_as_float(d0 & 0xFFFF0000u), ep[1], s);
                s = fmaf(__uint_as_float(d1 << 16), ep[2], s);
                s = fmaf(__uint_as_float(d1 & 0xFFFF0000u), ep[3], s);
                s = fmaf(__uint_as_float(d2 << 16), ep[4], s);
                s = fmaf(__uint_as_float(d2 & 0xFFFF0000u), ep[5], s);
                s = fmaf(__uint_as_float(d3 << 16), ep[6], s);
                s = fmaf(__uint_as_float(d3 & 0xFFFF0000u), ep[7], s);
            }
        }
        #pragma unroll
        for (int o = 8; o >= 1; o >>= 1) s += __shfl_xor(s, o, 64);
        if (cs == 0) den[row] = s;
    }
}

// ---------- out = relu( h / den ) ----------
__global__ __launch_bounds__(256) void final_kernel(const float* __restrict__ h,
        const float* __restrict__ den, float* __restrict__ out) {
    const int idx = blockIdx.x * 256 + threadIdx.x;
    const int i = idx >> 6;
    float v = h[idx] / den[i];
    out[idx] = v > 0.f ? v : 0.f;
}

extern "C" void kernel_launch(void* const* d_in, const int* in_sizes, int n_in,
                              void* d_out, int out_size, void* d_ws, size_t ws_size,
                              hipStream_t stream) {
    const float* A    = (const float*)d_in[0];
    const float* X    = (const float*)d_in[1];
    const float* W    = (const float*)d_in[2];
    const float* bias = (const float*)d_in[3];
    const float* phi  = (const float*)d_in[4];
    float* out = (float*)d_out;

    char* ws = (char*)d_ws;
    size_t off = 0;
    auto alloc = [&](size_t bytes) -> void* {
        void* p = ws + off;
        off += (bytes + 255) & ~(size_t)255;
        return p;
    };
    u8*    m8   = (u8*)alloc((size_t)NN * NB);
    short* XWf  = (short*)alloc((size_t)FOUT * NN * 2);
    float* y    = (float*)alloc((size_t)NN * 4);
    float* cb   = (float*)alloc(256);
    u32*   MbU  = (u32*)alloc(256);
    float* sjv  = (float*)alloc((size_t)NN * 4);
    float* aggr = (float*)alloc((size_t)NN * FOUT * 4);
    short* B2f  = (short*)alloc((size_t)FOUT * NN * 2);
    float* den  = (float*)alloc((size_t)NN * 4);
    float* h    = (float*)alloc((size_t)NN * FOUT * 4);

    xw_kernel<<<NN / 64, 256, 0, stream>>>(X, W, bias, phi, XWf, y, cb, MbU);
    mask_kernel<<<NN / 4, 256, 0, stream>>>(A, y, cb, m8, sjv, MbU);
    mm_kernel<false><<<NN / 32, 512, 0, stream>>>((const u64*)m8, XWf, aggr);
    ph3_kernel<<<640, 256, 0, stream>>>(aggr, bias, sjv, MbU, B2f, (const u64*)m8, den);
    mm_kernel<true><<<NN / 32, 512, 0, stream>>>((const u64*)m8, B2f, h);
    final_kernel<<<NN * 64 / 256, 256, 0, stream>>>(h, den, out);
}

// Round 11
// 170.277 us; speedup vs baseline: 2.1131x; 1.0381x over previous
//
#include <hip/hip_runtime.h>
#include <hip/hip_bf16.h>

#define NN 8192
#define FIN 128
#define FOUT 64
#define NWRD (NN / 64)       // 128 u64 words per mask row
#define NB (NN / 8)          // 1024 mask bytes per row

typedef __attribute__((ext_vector_type(8))) short short8;
typedef __attribute__((ext_vector_type(16))) float f32x16;
typedef unsigned int u32;
typedef unsigned char u8;
typedef unsigned long long u64;

static __device__ __forceinline__ short f2bf(float f) {
    union { __hip_bfloat16 h; short s; } u;
    u.h = __float2bfloat16(f);
    return u.s;
}

// one mask byte (8 bits) -> 8 bf16 {0,1.0} packed in short8
static __device__ __forceinline__ short8 expand8(u32 b) {
    u32 xl = ((b & 0xFu) * 0x00204081u) & 0x01010101u;
    u32 xh = (((b >> 4) & 0xFu) * 0x00204081u) & 0x01010101u;
    u32 d0 = __builtin_amdgcn_perm(0u, xl, 0x0C010C00u) * 0x3F80u;
    u32 d1 = __builtin_amdgcn_perm(0u, xl, 0x0C030C02u) * 0x3F80u;
    u32 d2 = __builtin_amdgcn_perm(0u, xh, 0x0C010C00u) * 0x3F80u;
    u32 d3 = __builtin_amdgcn_perm(0u, xh, 0x0C030C02u) * 0x3F80u;
    union { u32 u[4]; short8 v; } r;
    r.u[0] = d0; r.u[1] = d1; r.u[2] = d2; r.u[3] = d3;
    return r.v;
}

// ---------- XW (no bias) -> fragment-major bf16 + y = XW@phi_j + cb ----------
__global__ __launch_bounds__(256) void xw_kernel(const float* __restrict__ X,
        const float* __restrict__ W, const float* __restrict__ bias,
        const float* __restrict__ phi, short* __restrict__ XWf,
        float* __restrict__ y, float* __restrict__ cb) {
    __shared__ float Xs[64][FIN + 1];
    __shared__ short T[64][72];     // [node j][col c] bf16, padded
    __shared__ float yp[4][64];
    const int t = threadIdx.x;
    const int jb = blockIdx.x * 64;
    for (int u = t; u < 64 * FIN; u += 256) {
        int r = u >> 7, k = u & (FIN - 1);
        Xs[r][k] = X[(size_t)(jb + r) * FIN + k];
    }
    __syncthreads();
    const int j = t & 63;
    const int cg = t >> 6;
    float acc[16] = {};
    for (int k = 0; k < FIN; ++k) {
        float x = Xs[j][k];
        #pragma unroll
        for (int q = 0; q < 16; ++q)
            acc[q] = fmaf(x, W[k * FOUT + cg * 16 + q], acc[q]);
    }
    float ys = 0.f;
    union { short s[16]; short8 v[2]; } pk;
    #pragma unroll
    for (int q = 0; q < 16; ++q) {
        ys = fmaf(acc[q], phi[FOUT + cg * 16 + q], ys);
        pk.s[q] = f2bf(acc[q]);
    }
    *(short8*)&T[j][cg * 16] = pk.v[0];
    *(short8*)&T[j][cg * 16 + 8] = pk.v[1];
    yp[cg][j] = ys;
    __syncthreads();
    if (t < 64) y[jb + t] = yp[0][t] + yp[1][t] + yp[2][t] + yp[3][t];
    if (blockIdx.x == 0 && t == 0) {
        float s = 0.f;
        for (int c = 0; c < FOUT; ++c) s = fmaf(bias[c], phi[FOUT + c], s);
        cb[0] = s;
    }
    // fragment-major: frag fi = ktile*2 + colgroup; lane l: B[k=(l>>5)*8+e][c=(l&31)]
    #pragma unroll
    for (int uu = 0; uu < 2; ++uu) {
        int u = t + uu * 256;
        int f = u >> 6, ln = u & 63;
        int c = (f & 1) * 32 + (ln & 31);
        int j0 = (f >> 1) * 16 + (ln >> 5) * 8;
        union { short s[8]; short8 v; } w8;
        #pragma unroll
        for (int e = 0; e < 8; ++e) w8.s[e] = T[j0 + e][c];
        size_t fg = ((size_t)(jb >> 4) + (f >> 1)) * 2 + (f & 1);
        *(short8*)&XWf[fg * 512 + ln * 8] = w8.v;
    }
}

// ---------- A -> bitmask bytes; fused exact sj_i = A@y + cb; block max ----------
__global__ __launch_bounds__(256) void mask_kernel(const float* __restrict__ A,
        const float* __restrict__ y, const float* __restrict__ cb,
        u8* __restrict__ m8, float* __restrict__ sjv, float* __restrict__ maxp) {
    __shared__ float4 ys4[NN / 4];
    const float* ysp = (const float*)ys4;
    for (int i = threadIdx.x; i < NN / 4; i += 256)
        ys4[i] = ((const float4*)y)[i];
    __syncthreads();
    const int t = threadIdx.x;
    const int row = blockIdx.x * 4 + (t >> 6);
    const int l = t & 63;
    const float* ar = A + (size_t)row * NN + l * 8;
    u8* mr = m8 + (size_t)row * NB + l;
    float s = 0.f;
    #pragma unroll 2
    for (int kc = 0; kc < NN; kc += 512) {
        float4 a = *(const float4*)(ar + kc);
        float4 b = *(const float4*)(ar + kc + 4);
        float4 y0 = *(const float4*)(ysp + kc + l * 8);
        float4 y1 = *(const float4*)(ysp + kc + l * 8 + 4);
        s = fmaf(a.x, y0.x, s); s = fmaf(a.y, y0.y, s);
        s = fmaf(a.z, y0.z, s); s = fmaf(a.w, y0.w, s);
        s = fmaf(b.x, y1.x, s); s = fmaf(b.y, y1.y, s);
        s = fmaf(b.z, y1.z, s); s = fmaf(b.w, y1.w, s);
        u32 x0 = __float_as_uint(a.x), x1 = __float_as_uint(a.y);
        u32 x2 = __float_as_uint(a.z), x3 = __float_as_uint(a.w);
        u32 x4 = __float_as_uint(b.x), x5 = __float_as_uint(b.y);
        u32 x6 = __float_as_uint(b.z), x7 = __float_as_uint(b.w);
        u32 ylo = __builtin_amdgcn_perm(x1, x0, 0x0C0C0703u) |
                  __builtin_amdgcn_perm(x3, x2, 0x07030C0Cu);
        u32 yhi = __builtin_amdgcn_perm(x5, x4, 0x0C0C0703u) |
                  __builtin_amdgcn_perm(x7, x6, 0x07030C0Cu);
        u32 nlo = (((ylo >> 5) & 0x01010101u) * 0x01020408u) >> 24;
        u32 nhi = (((yhi >> 5) & 0x01010101u) * 0x01020408u) >> 24;
        mr[kc >> 3] = (u8)(nlo | (nhi << 4));
    }
    #pragma unroll
    for (int o = 32; o >= 1; o >>= 1) s += __shfl_down(s, o, 64);
    __shared__ float red[4];
    float sj = s + cb[0];
    if (l == 0) { sjv[row] = sj; red[t >> 6] = sj; }
    __syncthreads();
    if (t == 0)
        maxp[blockIdx.x] = fmaxf(fmaxf(red[0], red[1]), fmaxf(red[2], red[3]));
}

__global__ __launch_bounds__(256) void maxfin_kernel(const float* __restrict__ maxp,
                                                     float* __restrict__ Mb) {
    float m = -3.0e38f;
    for (int i = threadIdx.x; i < 2048; i += 256) m = fmaxf(m, maxp[i]);
    #pragma unroll
    for (int o = 32; o >= 1; o >>= 1) m = fmaxf(m, __shfl_down(m, o, 64));
    __shared__ float red[4];
    if ((threadIdx.x & 63) == 0) red[threadIdx.x >> 6] = m;
    __syncthreads();
    if (threadIdx.x == 0)
        Mb[0] = fmaxf(fmaxf(red[0], red[1]), fmaxf(red[2], red[3]));
}

// ---------- mask(A[+I]) @ B : full-K per block, no split-K partials ----------
// 256 blocks x 32 rows; 8 waves each own K=1024; B-frags global->VGPR (L2-hit).
// EPI: fuse out = relu(h/den) into the epilogue.
template <bool DIAG, bool EPI>
__global__ __launch_bounds__(512) void mm_kernel(const u64* __restrict__ mask,
        const short* __restrict__ Bfrag, const float* __restrict__ den,
        float* __restrict__ outv) {
    __shared__ float red[8][2048];
    const int t = threadIdx.x;
    const int w = t >> 6;          // wave 0..7
    const int l = t & 63;
    const int brow = blockIdx.x * 32;
    const int r0 = brow + (l & 31);
    const int kh = l >> 5;
    const int k0 = w * 1024;       // wave's K-chunk base

    const u64* mp = mask + (size_t)r0 * NWRD + (k0 >> 6);
    u64 mw[16];
    #pragma unroll
    for (int q = 0; q < 16; ++q) mw[q] = mp[q];

    f32x16 acc0 = {}, acc1 = {};
    const short* bp = Bfrag + (size_t)(k0 >> 4) * 2 * 512 + l * 8;

    short8 f0a, f1a, f0b, f1b, f0c, f1c, f0d, f1d;
    f0a = *(const short8*)(bp + 0 * 512);  f1a = *(const short8*)(bp + 1 * 512);
    f0b = *(const short8*)(bp + 2 * 512);  f1b = *(const short8*)(bp + 3 * 512);
    f0c = *(const short8*)(bp + 4 * 512);  f1c = *(const short8*)(bp + 5 * 512);
    f0d = *(const short8*)(bp + 6 * 512);  f1d = *(const short8*)(bp + 7 * 512);

    #pragma unroll
    for (int kt4 = 0; kt4 < 16; ++kt4) {
        #pragma unroll
        for (int pp = 0; pp < 4; ++pp) {
            const int kt = kt4 * 4 + pp;
            const int bidx = kt * 2 + kh;
            u32 b = (u32)(mw[bidx >> 3] >> ((bidx & 7) * 8)) & 0xFFu;
            if (DIAG) {
                u32 d = (u32)(r0 - (k0 + kt * 16 + kh * 8));
                if (d < 8u) b |= 1u << d;
            }
            short8 a = expand8(b);
            short8 bf0 = (pp == 0) ? f0a : (pp == 1) ? f0b : (pp == 2) ? f0c : f0d;
            short8 bf1 = (pp == 0) ? f1a : (pp == 1) ? f1b : (pp == 2) ? f1c : f1d;
            acc0 = __builtin_amdgcn_mfma_f32_32x32x16_bf16(a, bf0, acc0, 0, 0, 0);
            acc1 = __builtin_amdgcn_mfma_f32_32x32x16_bf16(a, bf1, acc1, 0, 0, 0);
            if (kt + 4 < 64) {
                short8 n0 = *(const short8*)(bp + ((kt + 4) * 2 + 0) * 512);
                short8 n1 = *(const short8*)(bp + ((kt + 4) * 2 + 1) * 512);
                if (pp == 0) { f0a = n0; f1a = n1; }
                else if (pp == 1) { f0b = n0; f1b = n1; }
                else if (pp == 2) { f0c = n0; f1c = n1; }
                else { f0d = n0; f1d = n1; }
            }
        }
    }

    // cross-wave reduce in LDS: D layout col=lane&31, row=(q&3)+8*(q>>2)+4*(lane>>5)
    const int cc = l & 31;
    const int rq4 = 4 * (l >> 5);
    #pragma unroll
    for (int q = 0; q < 16; ++q) {
        int row = (q & 3) + 8 * (q >> 2) + rq4;
        red[w][row * 64 + cc] = acc0[q];
        red[w][row * 64 + 32 + cc] = acc1[q];
    }
    __syncthreads();
    float4 s = {0.f, 0.f, 0.f, 0.f};
    #pragma unroll
    for (int ww = 0; ww < 8; ++ww) {
        float4 v = *(const float4*)&red[ww][t * 4];
        s.x += v.x; s.y += v.y; s.z += v.z; s.w += v.w;
    }
    if (EPI) {
        const float d = den[brow + (t >> 4)];   // row for this float4
        s.x /= d; s.y /= d; s.z /= d; s.w /= d;
        s.x = s.x > 0.f ? s.x : 0.f;
        s.y = s.y > 0.f ? s.y : 0.f;
        s.z = s.z > 0.f ? s.z : 0.f;
        s.w = s.w > 0.f ? s.w : 0.f;
    }
    *(float4*)&outv[(size_t)brow * 64 + t * 4] = s;
}

// ---------- fused: bbuild (blocks 0..127) | den (blocks 128..639) ----------
__global__ __launch_bounds__(256) void ph3_kernel(const float* __restrict__ aggr,
        const float* __restrict__ bias, const float* __restrict__ sjv,
        const float* __restrict__ Mb, short* __restrict__ B2f,
        const u64* __restrict__ mask, float* __restrict__ den) {
    __shared__ union { short Tt[64][72]; float es[NN]; } sm;
    const int b = blockIdx.x, t = threadIdx.x;
    if (b < 128) {
        // B2 = bf16(e_j * (agg_j + bias)) in fragment-major
        const int jb = b * 64;
        const int jl = t >> 2;
        const int j = jb + jl;
        const int cg = (t & 3) * 16;
        const float4* p = (const float4*)&aggr[(size_t)j * 64 + cg];
        float4 q0 = p[0], q1 = p[1], q2 = p[2], q3 = p[3];
        float v[16] = {q0.x, q0.y, q0.z, q0.w, q1.x, q1.y, q1.z, q1.w,
                       q2.x, q2.y, q2.z, q2.w, q3.x, q3.y, q3.z, q3.w};
        const float e = __expf(sjv[j] - Mb[0]);
        union { short s[16]; short8 w[2]; } pk;
        #pragma unroll
        for (int q = 0; q < 16; ++q) pk.s[q] = f2bf((v[q] + bias[cg + q]) * e);
        *(short8*)&sm.Tt[jl][cg] = pk.w[0];
        *(short8*)&sm.Tt[jl][cg + 8] = pk.w[1];
        __syncthreads();
        #pragma unroll
        for (int uu = 0; uu < 2; ++uu) {
            int u = t + uu * 256;
            int f = u >> 6, ln = u & 63;
            int c = (f & 1) * 32 + (ln & 31);
            int j0 = (f >> 1) * 16 + (ln >> 5) * 8;
            union { short s[8]; short8 v; } w8;
            #pragma unroll
            for (int e8 = 0; e8 < 8; ++e8) w8.s[e8] = sm.Tt[j0 + e8][c];
            size_t fg = ((size_t)(jb >> 4) + (f >> 1)) * 2 + (f & 1);
            *(short8*)&B2f[fg * 512 + ln * 8] = w8.v;
        }
    } else {
        // den_i = sum_{j in mask+I} e_j
        const float M = Mb[0];
        for (int i = t; i < NN; i += 256) sm.es[i] = __expf(sjv[i] - M);
        __syncthreads();
        const float* es = sm.es;
        const int row = (b - 128) * 16 + (t >> 4);
        const int cs = t & 15;
        const u64* mp = mask + (size_t)row * NWRD + cs * 8;
        float s = 0.f;
        #pragma unroll
        for (int wd = 0; wd < 8; ++wd) {
            u64 mwv = mp[wd];
            const int kg = cs * 512 + wd * 64;
            u32 d = (u32)(row - kg);
            if (d < 64u) mwv |= 1ull << d;     // +I
            #pragma unroll
            for (int b8 = 0; b8 < 8; ++b8) {
                u32 by = (u32)(mwv >> (b8 * 8)) & 0xFFu;
                u32 xl = ((by & 0xFu) * 0x00204081u) & 0x01010101u;
                u32 xh = (((by >> 4) & 0xFu) * 0x00204081u) & 0x01010101u;
                u32 d0 = __builtin_amdgcn_perm(0u, xl, 0x0C010C00u) * 0x3F80u;
                u32 d1 = __builtin_amdgcn_perm(0u, xl, 0x0C030C02u) * 0x3F80u;
                u32 d2 = __builtin_amdgcn_perm(0u, xh, 0x0C010C00u) * 0x3F80u;
                u32 d3 = __builtin_amdgcn_perm(0u, xh, 0x0C030C02u) * 0x3F80u;
                const float* ep = es + kg + b8 * 8;
                s = fmaf(__uint_as_float(d0 << 16), ep[0], s);
                s = fmaf(__uint_as_float(d0 & 0xFFFF0000u), ep[1], s);
                s = fmaf(__uint_as_float(d1 << 16), ep[2], s);
                s = fmaf(__uint_as_float(d1 & 0xFFFF0000u), ep[3], s);
                s = fmaf(__uint_as_float(d2 << 16), ep[4], s);
                s = fmaf(__uint_as_float(d2 & 0xFFFF0000u), ep[5], s);
                s = fmaf(__uint_as_float(d3 << 16), ep[6], s);
                s = fmaf(__uint_as_float(d3 & 0xFFFF0000u), ep[7], s);
            }
        }
        #pragma unroll
        for (int o = 8; o >= 1; o >>= 1) s += __shfl_xor(s, o, 64);
        if (cs == 0) den[row] = s;
    }
}

extern "C" void kernel_launch(void* const* d_in, const int* in_sizes, int n_in,
                              void* d_out, int out_size, void* d_ws, size_t ws_size,
                              hipStream_t stream) {
    const float* A    = (const float*)d_in[0];
    const float* X    = (const float*)d_in[1];
    const float* W    = (const float*)d_in[2];
    const float* bias = (const float*)d_in[3];
    const float* phi  = (const float*)d_in[4];
    float* out = (float*)d_out;

    char* ws = (char*)d_ws;
    size_t off = 0;
    auto alloc = [&](size_t bytes) -> void* {
        void* p = ws + off;
        off += (bytes + 255) & ~(size_t)255;
        return p;
    };
    u8*    m8   = (u8*)alloc((size_t)NN * NB);
    short* XWf  = (short*)alloc((size_t)FOUT * NN * 2);
    float* y    = (float*)alloc((size_t)NN * 4);
    float* cb   = (float*)alloc(256);
    float* sjv  = (float*)alloc((size_t)NN * 4);
    float* maxp = (float*)alloc(2048 * 4);
    float* Mb   = (float*)alloc(256);
    float* aggr = (float*)alloc((size_t)NN * FOUT * 4);
    short* B2f  = (short*)alloc((size_t)FOUT * NN * 2);
    float* den  = (float*)alloc((size_t)NN * 4);

    xw_kernel<<<NN / 64, 256, 0, stream>>>(X, W, bias, phi, XWf, y, cb);
    mask_kernel<<<NN / 4, 256, 0, stream>>>(A, y, cb, m8, sjv, maxp);
    maxfin_kernel<<<1, 256, 0, stream>>>(maxp, Mb);
    mm_kernel<false, false><<<NN / 32, 512, 0, stream>>>(
        (const u64*)m8, XWf, nullptr, aggr);
    ph3_kernel<<<640, 256, 0, stream>>>(aggr, bias, sjv, Mb, B2f, (const u64*)m8, den);
    mm_kernel<true, true><<<NN / 32, 512, 0, stream>>>(
        (const u64*)m8, B2f, den, out);
}

// Round 12
// 127.303 us; speedup vs baseline: 2.8264x; 1.3376x over previous
//
#include <hip/hip_runtime.h>
#include <hip/hip_bf16.h>

#define NN 8192
#define FIN 128
#define FOUT 64
#define NWRD (NN / 64)       // 128 u64 words per mask row
#define NB (NN / 8)          // 1024 mask bytes per row

typedef __attribute__((ext_vector_type(8))) short short8;
typedef __attribute__((ext_vector_type(16))) float f32x16;
typedef unsigned int u32;
typedef unsigned char u8;
typedef unsigned long long u64;

static __device__ __forceinline__ short f2bf(float f) {
    union { __hip_bfloat16 h; short s; } u;
    u.h = __float2bfloat16(f);
    return u.s;
}

// one mask byte (8 bits) -> 8 bf16 {0,1.0} packed in short8
static __device__ __forceinline__ short8 expand8(u32 b) {
    u32 xl = ((b & 0xFu) * 0x00204081u) & 0x01010101u;
    u32 xh = (((b >> 4) & 0xFu) * 0x00204081u) & 0x01010101u;
    u32 d0 = __builtin_amdgcn_perm(0u, xl, 0x0C010C00u) * 0x3F80u;
    u32 d1 = __builtin_amdgcn_perm(0u, xl, 0x0C030C02u) * 0x3F80u;
    u32 d2 = __builtin_amdgcn_perm(0u, xh, 0x0C010C00u) * 0x3F80u;
    u32 d3 = __builtin_amdgcn_perm(0u, xh, 0x0C030C02u) * 0x3F80u;
    union { u32 u[4]; short8 v; } r;
    r.u[0] = d0; r.u[1] = d1; r.u[2] = d2; r.u[3] = d3;
    return r.v;
}

// ---------- XW (no bias) -> fragment-major bf16 + y = XW@phi_j + cb ----------
__global__ __launch_bounds__(256) void xw_kernel(const float* __restrict__ X,
        const float* __restrict__ W, const float* __restrict__ bias,
        const float* __restrict__ phi, short* __restrict__ XWf,
        float* __restrict__ y, float* __restrict__ cb) {
    __shared__ float Xs[64][FIN + 1];
    __shared__ short T[64][72];     // [node j][col c] bf16, padded
    __shared__ float yp[4][64];
    const int t = threadIdx.x;
    const int jb = blockIdx.x * 64;
    for (int u = t; u < 64 * FIN; u += 256) {
        int r = u >> 7, k = u & (FIN - 1);
        Xs[r][k] = X[(size_t)(jb + r) * FIN + k];
    }
    __syncthreads();
    const int j = t & 63;
    const int cg = t >> 6;
    float acc[16] = {};
    for (int k = 0; k < FIN; ++k) {
        float x = Xs[j][k];
        #pragma unroll
        for (int q = 0; q < 16; ++q)
            acc[q] = fmaf(x, W[k * FOUT + cg * 16 + q], acc[q]);
    }
    float ys = 0.f;
    union { short s[16]; short8 v[2]; } pk;
    #pragma unroll
    for (int q = 0; q < 16; ++q) {
        ys = fmaf(acc[q], phi[FOUT + cg * 16 + q], ys);
        pk.s[q] = f2bf(acc[q]);
    }
    *(short8*)&T[j][cg * 16] = pk.v[0];
    *(short8*)&T[j][cg * 16 + 8] = pk.v[1];
    yp[cg][j] = ys;
    __syncthreads();
    if (t < 64) y[jb + t] = yp[0][t] + yp[1][t] + yp[2][t] + yp[3][t];
    if (blockIdx.x == 0 && t == 0) {
        float s = 0.f;
        for (int c = 0; c < FOUT; ++c) s = fmaf(bias[c], phi[FOUT + c], s);
        cb[0] = s;
    }
    // fragment-major: frag fi = ktile*2 + colgroup; lane l: B[k=(l>>5)*8+e][c=(l&31)]
    #pragma unroll
    for (int uu = 0; uu < 2; ++uu) {
        int u = t + uu * 256;
        int f = u >> 6, ln = u & 63;
        int c = (f & 1) * 32 + (ln & 31);
        int j0 = (f >> 1) * 16 + (ln >> 5) * 8;
        union { short s[8]; short8 v; } w8;
        #pragma unroll
        for (int e = 0; e < 8; ++e) w8.s[e] = T[j0 + e][c];
        size_t fg = ((size_t)(jb >> 4) + (f >> 1)) * 2 + (f & 1);
        *(short8*)&XWf[fg * 512 + ln * 8] = w8.v;
    }
}

// ---------- A -> bitmask bytes; fused exact sj_i = A@y + cb; block max ----------
// y staged in LDS with XOR-swizzled float4 index (kills 16-way bank conflict).
__global__ __launch_bounds__(256) void mask_kernel(const float* __restrict__ A,
        const float* __restrict__ y, const float* __restrict__ cb,
        u8* __restrict__ m8, float* __restrict__ sjv, float* __restrict__ maxp) {
    __shared__ float4 ys4[NN / 4];
    for (int i = threadIdx.x; i < NN / 4; i += 256)
        ys4[i ^ ((i >> 3) & 7)] = ((const float4*)y)[i];
    __syncthreads();
    const int t = threadIdx.x;
    const int row = blockIdx.x * 4 + (t >> 6);
    const int l = t & 63;
    const float* ar = A + (size_t)row * NN + l * 8;
    u8* mr = m8 + (size_t)row * NB + l;
    float s = 0.f;
    #pragma unroll 2
    for (int kc = 0; kc < NN; kc += 512) {
        float4 a = *(const float4*)(ar + kc);
        float4 b = *(const float4*)(ar + kc + 4);
        const int f0 = (kc >> 2) + l * 2;
        const int sw = (f0 >> 3) & 7;       // same for f0 and f0+1 (f0 even)
        float4 y0 = ys4[f0 ^ sw];
        float4 y1 = ys4[(f0 + 1) ^ sw];
        s = fmaf(a.x, y0.x, s); s = fmaf(a.y, y0.y, s);
        s = fmaf(a.z, y0.z, s); s = fmaf(a.w, y0.w, s);
        s = fmaf(b.x, y1.x, s); s = fmaf(b.y, y1.y, s);
        s = fmaf(b.z, y1.z, s); s = fmaf(b.w, y1.w, s);
        u32 x0 = __float_as_uint(a.x), x1 = __float_as_uint(a.y);
        u32 x2 = __float_as_uint(a.z), x3 = __float_as_uint(a.w);
        u32 x4 = __float_as_uint(b.x), x5 = __float_as_uint(b.y);
        u32 x6 = __float_as_uint(b.z), x7 = __float_as_uint(b.w);
        u32 ylo = __builtin_amdgcn_perm(x1, x0, 0x0C0C0703u) |
                  __builtin_amdgcn_perm(x3, x2, 0x07030C0Cu);
        u32 yhi = __builtin_amdgcn_perm(x5, x4, 0x0C0C0703u) |
                  __builtin_amdgcn_perm(x7, x6, 0x07030C0Cu);
        u32 nlo = (((ylo >> 5) & 0x01010101u) * 0x01020408u) >> 24;
        u32 nhi = (((yhi >> 5) & 0x01010101u) * 0x01020408u) >> 24;
        mr[kc >> 3] = (u8)(nlo | (nhi << 4));
    }
    #pragma unroll
    for (int o = 32; o >= 1; o >>= 1) s += __shfl_down(s, o, 64);
    __shared__ float red[4];
    float sj = s + cb[0];
    if (l == 0) { sjv[row] = sj; red[t >> 6] = sj; }
    __syncthreads();
    if (t == 0)
        maxp[blockIdx.x] = fmaxf(fmaxf(red[0], red[1]), fmaxf(red[2], red[3]));
}

__global__ __launch_bounds__(256) void maxfin_kernel(const float* __restrict__ maxp,
                                                     float* __restrict__ Mb) {
    float m = -3.0e38f;
    for (int i = threadIdx.x; i < 2048; i += 256) m = fmaxf(m, maxp[i]);
    #pragma unroll
    for (int o = 32; o >= 1; o >>= 1) m = fmaxf(m, __shfl_down(m, o, 64));
    __shared__ float red[4];
    if ((threadIdx.x & 63) == 0) red[threadIdx.x >> 6] = m;
    __syncthreads();
    if (threadIdx.x == 0)
        Mb[0] = fmaxf(fmaxf(red[0], red[1]), fmaxf(red[2], red[3]));
}

// ---------- mask(A[+I]) @ B : full-K per block, no split-K partials ----------
// 256 blocks x 32 rows; 8 waves each own K=1024; B-frags global->VGPR (L2-hit).
// EPI: fuse out = relu(h/den) into the epilogue.
template <bool DIAG, bool EPI>
__global__ __launch_bounds__(512) void mm_kernel(const u64* __restrict__ mask,
        const short* __restrict__ Bfrag, const float* __restrict__ den,
        float* __restrict__ outv) {
    __shared__ float red[8][2048];
    const int t = threadIdx.x;
    const int w = t >> 6;          // wave 0..7
    const int l = t & 63;
    const int brow = blockIdx.x * 32;
    const int r0 = brow + (l & 31);
    const int kh = l >> 5;
    const int k0 = w * 1024;       // wave's K-chunk base

    const u64* mp = mask + (size_t)r0 * NWRD + (k0 >> 6);
    u64 mw[16];
    #pragma unroll
    for (int q = 0; q < 16; ++q) mw[q] = mp[q];

    f32x16 acc0 = {}, acc1 = {};
    const short* bp = Bfrag + (size_t)(k0 >> 4) * 2 * 512 + l * 8;

    short8 f0a, f1a, f0b, f1b, f0c, f1c, f0d, f1d;
    f0a = *(const short8*)(bp + 0 * 512);  f1a = *(const short8*)(bp + 1 * 512);
    f0b = *(const short8*)(bp + 2 * 512);  f1b = *(const short8*)(bp + 3 * 512);
    f0c = *(const short8*)(bp + 4 * 512);  f1c = *(const short8*)(bp + 5 * 512);
    f0d = *(const short8*)(bp + 6 * 512);  f1d = *(const short8*)(bp + 7 * 512);

    #pragma unroll
    for (int kt4 = 0; kt4 < 16; ++kt4) {
        #pragma unroll
        for (int pp = 0; pp < 4; ++pp) {
            const int kt = kt4 * 4 + pp;
            const int bidx = kt * 2 + kh;
            u32 b = (u32)(mw[bidx >> 3] >> ((bidx & 7) * 8)) & 0xFFu;
            if (DIAG) {
                u32 d = (u32)(r0 - (k0 + kt * 16 + kh * 8));
                if (d < 8u) b |= 1u << d;
            }
            short8 a = expand8(b);
            short8 bf0 = (pp == 0) ? f0a : (pp == 1) ? f0b : (pp == 2) ? f0c : f0d;
            short8 bf1 = (pp == 0) ? f1a : (pp == 1) ? f1b : (pp == 2) ? f1c : f1d;
            acc0 = __builtin_amdgcn_mfma_f32_32x32x16_bf16(a, bf0, acc0, 0, 0, 0);
            acc1 = __builtin_amdgcn_mfma_f32_32x32x16_bf16(a, bf1, acc1, 0, 0, 0);
            if (kt + 4 < 64) {
                short8 n0 = *(const short8*)(bp + ((kt + 4) * 2 + 0) * 512);
                short8 n1 = *(const short8*)(bp + ((kt + 4) * 2 + 1) * 512);
                if (pp == 0) { f0a = n0; f1a = n1; }
                else if (pp == 1) { f0b = n0; f1b = n1; }
                else if (pp == 2) { f0c = n0; f1c = n1; }
                else { f0d = n0; f1d = n1; }
            }
        }
    }

    // cross-wave reduce in LDS: D layout col=lane&31, row=(q&3)+8*(q>>2)+4*(lane>>5)
    const int cc = l & 31;
    const int rq4 = 4 * (l >> 5);
    #pragma unroll
    for (int q = 0; q < 16; ++q) {
        int row = (q & 3) + 8 * (q >> 2) + rq4;
        red[w][row * 64 + cc] = acc0[q];
        red[w][row * 64 + 32 + cc] = acc1[q];
    }
    __syncthreads();
    float4 s = {0.f, 0.f, 0.f, 0.f};
    #pragma unroll
    for (int ww = 0; ww < 8; ++ww) {
        float4 v = *(const float4*)&red[ww][t * 4];
        s.x += v.x; s.y += v.y; s.z += v.z; s.w += v.w;
    }
    if (EPI) {
        const float d = den[brow + (t >> 4)];   // row for this float4
        s.x /= d; s.y /= d; s.z /= d; s.w /= d;
        s.x = s.x > 0.f ? s.x : 0.f;
        s.y = s.y > 0.f ? s.y : 0.f;
        s.z = s.z > 0.f ? s.z : 0.f;
        s.w = s.w > 0.f ? s.w : 0.f;
    }
    *(float4*)&outv[(size_t)brow * 64 + t * 4] = s;
}

// ---------- fused: bbuild (blocks 0..127) | den (blocks 128..639) ----------
// den's es[] staged with XOR swizzle (cs bits into bank bits) -> conflict-free.
__global__ __launch_bounds__(256) void ph3_kernel(const float* __restrict__ aggr,
        const float* __restrict__ bias, const float* __restrict__ sjv,
        const float* __restrict__ Mb, short* __restrict__ B2f,
        const u64* __restrict__ mask, float* __restrict__ den) {
    __shared__ union { short Tt[64][72]; float es[NN]; } sm;
    const int b = blockIdx.x, t = threadIdx.x;
    if (b < 128) {
        // B2 = bf16(e_j * (agg_j + bias)) in fragment-major
        const int jb = b * 64;
        const int jl = t >> 2;
        const int j = jb + jl;
        const int cg = (t & 3) * 16;
        const float4* p = (const float4*)&aggr[(size_t)j * 64 + cg];
        float4 q0 = p[0], q1 = p[1], q2 = p[2], q3 = p[3];
        float v[16] = {q0.x, q0.y, q0.z, q0.w, q1.x, q1.y, q1.z, q1.w,
                       q2.x, q2.y, q2.z, q2.w, q3.x, q3.y, q3.z, q3.w};
        const float e = __expf(sjv[j] - Mb[0]);
        union { short s[16]; short8 w[2]; } pk;
        #pragma unroll
        for (int q = 0; q < 16; ++q) pk.s[q] = f2bf((v[q] + bias[cg + q]) * e);
        *(short8*)&sm.Tt[jl][cg] = pk.w[0];
        *(short8*)&sm.Tt[jl][cg + 8] = pk.w[1];
        __syncthreads();
        #pragma unroll
        for (int uu = 0; uu < 2; ++uu) {
            int u = t + uu * 256;
            int f = u >> 6, ln = u & 63;
            int c = (f & 1) * 32 + (ln & 31);
            int j0 = (f >> 1) * 16 + (ln >> 5) * 8;
            union { short s[8]; short8 v; } w8;
            #pragma unroll
            for (int e8 = 0; e8 < 8; ++e8) w8.s[e8] = sm.Tt[j0 + e8][c];
            size_t fg = ((size_t)(jb >> 4) + (f >> 1)) * 2 + (f & 1);
            *(short8*)&B2f[fg * 512 + ln * 8] = w8.v;
        }
    } else {
        // den_i = sum_{j in mask+I} e_j  (swizzled es: idx ^ ((idx>>9)&31))
        const float M = Mb[0];
        for (int i = t; i < NN; i += 256)
            sm.es[i ^ ((i >> 9) & 31)] = __expf(sjv[i] - M);
        __syncthreads();
        const float* es = sm.es;
        const int row = (b - 128) * 16 + (t >> 4);
        const int cs = t & 15;
        const u64* mp = mask + (size_t)row * NWRD + cs * 8;
        float s = 0.f;
        #pragma unroll
        for (int wd = 0; wd < 8; ++wd) {
            u64 mwv = mp[wd];
            const int kg = cs * 512 + wd * 64;
            u32 d = (u32)(row - kg);
            if (d < 64u) mwv |= 1ull << d;     // +I
            #pragma unroll
            for (int b8 = 0; b8 < 8; ++b8) {
                u32 by = (u32)(mwv >> (b8 * 8)) & 0xFFu;
                u32 xl = ((by & 0xFu) * 0x00204081u) & 0x01010101u;
                u32 xh = (((by >> 4) & 0xFu) * 0x00204081u) & 0x01010101u;
                u32 d0 = __builtin_amdgcn_perm(0u, xl, 0x0C010C00u) * 0x3F80u;
                u32 d1 = __builtin_amdgcn_perm(0u, xl, 0x0C030C02u) * 0x3F80u;
                u32 d2 = __builtin_amdgcn_perm(0u, xh, 0x0C010C00u) * 0x3F80u;
                u32 d3 = __builtin_amdgcn_perm(0u, xh, 0x0C030C02u) * 0x3F80u;
                const int base = kg + b8 * 8;   // (base>>9)&31 == cs
                s = fmaf(__uint_as_float(d0 << 16),          es[(base + 0) ^ cs], s);
                s = fmaf(__uint_as_float(d0 & 0xFFFF0000u),  es[(base + 1) ^ cs], s);
                s = fmaf(__uint_as_float(d1 << 16),          es[(base + 2) ^ cs], s);
                s = fmaf(__uint_as_float(d1 & 0xFFFF0000u),  es[(base + 3) ^ cs], s);
                s = fmaf(__uint_as_float(d2 << 16),          es[(base + 4) ^ cs], s);
                s = fmaf(__uint_as_float(d2 & 0xFFFF0000u),  es[(base + 5) ^ cs], s);
                s = fmaf(__uint_as_float(d3 << 16),          es[(base + 6) ^ cs], s);
                s = fmaf(__uint_as_float(d3 & 0xFFFF0000u),  es[(base + 7) ^ cs], s);
            }
        }
        #pragma unroll
        for (int o = 8; o >= 1; o >>= 1) s += __shfl_xor(s, o, 64);
        if (cs == 0) den[row] = s;
    }
}

extern "C" void kernel_launch(void* const* d_in, const int* in_sizes, int n_in,
                              void* d_out, int out_size, void* d_ws, size_t ws_size,
                              hipStream_t stream) {
    const float* A    = (const float*)d_in[0];
    const float* X    = (const float*)d_in[1];
    const float* W    = (const float*)d_in[2];
    const float* bias = (const float*)d_in[3];
    const float* phi  = (const float*)d_in[4];
    float* out = (float*)d_out;

    char* ws = (char*)d_ws;
    size_t off = 0;
    auto alloc = [&](size_t bytes) -> void* {
        void* p = ws + off;
        off += (bytes + 255) & ~(size_t)255;
        return p;
    };
    u8*    m8   = (u8*)alloc((size_t)NN * NB);
    short* XWf  = (short*)alloc((size_t)FOUT * NN * 2);
    float* y    = (float*)alloc((size_t)NN * 4);
    float* cb   = (float*)alloc(256);
    float* sjv  = (float*)alloc((size_t)NN * 4);
    float* maxp = (float*)alloc(2048 * 4);
    float* Mb   = (float*)alloc(256);
    float* aggr = (float*)alloc((size_t)NN * FOUT * 4);
    short* B2f  = (short*)alloc((size_t)FOUT * NN * 2);
    float* den  = (float*)alloc((size_t)NN * 4);

    xw_kernel<<<NN / 64, 256, 0, stream>>>(X, W, bias, phi, XWf, y, cb);
    mask_kernel<<<NN / 4, 256, 0, stream>>>(A, y, cb, m8, sjv, maxp);
    maxfin_kernel<<<1, 256, 0, stream>>>(maxp, Mb);
    mm_kernel<false, false><<<NN / 32, 512, 0, stream>>>(
        (const u64*)m8, XWf, nullptr, aggr);
    ph3_kernel<<<640, 256, 0, stream>>>(aggr, bias, sjv, Mb, B2f, (const u64*)m8, den);
    mm_kernel<true, true><<<NN / 32, 512, 0, stream>>>(
        (const u64*)m8, B2f, den, out);
}